// Round 2
// baseline (410.750 us; speedup 1.0000x reference)
//
#include <hip/hip_runtime.h>
#include <stdint.h>

// Block-sparse linear: out[8192,4096] = x @ W^T + bias, W BSR 64x64 blocks,
// 32 nnz blocks per block-row. fp32->bf16 convert into d_ws, then MFMA bf16
// GEMM. R2: XOR-swizzled LDS layout (kills 16-way ds_read_b128 bank
// conflicts: SQ_LDS_BANK_CONFLICT was 5e7 = ~42% of GEMM cycles), cols[]
// preloaded to registers + __shfl (removes dependent global load from K-loop).

#define BATCH   8192
#define IN_F    4096
#define OUT_F   4096
#define BS      64
#define NROW    64
#define NNZB    2048
#define BM      256                       // batch rows per workgroup
#define LDS_A_BYTES (BM * BS * 2)         // 32768
#define LDS_B_BYTES (BS * BS * 2)         // 8192

typedef float f32x4 __attribute__((ext_vector_type(4)));
typedef short s16x8 __attribute__((ext_vector_type(8)));   // 8 x bf16

__device__ __forceinline__ void async_copy16(const void* g, void* l) {
  // global -> LDS direct DMA, 16 B/lane. LDS side is base + lane*16 (fixed).
  __builtin_amdgcn_global_load_lds(
      (__attribute__((address_space(1))) void*)g,
      (__attribute__((address_space(3))) void*)l, 16, 0, 0);
}

__device__ __forceinline__ unsigned short f32_to_bf16(float f) {
  union { float f; uint32_t u; } v; v.f = f;
  return (unsigned short)((v.u + 0x7FFFu + ((v.u >> 16) & 1u)) >> 16);
}

__global__ void cvt_kernel(const float4* __restrict__ in,
                           ushort4* __restrict__ out, int n4) {
  int i = blockIdx.x * blockDim.x + threadIdx.x;
  if (i < n4) {
    float4 v = in[i];
    ushort4 o;
    o.x = f32_to_bf16(v.x); o.y = f32_to_bf16(v.y);
    o.z = f32_to_bf16(v.z); o.w = f32_to_bf16(v.w);
    out[i] = o;
  }
}

// GEMM: grid (NROW=64, BATCH/BM=32), block 256 = 4 waves.
// Wave w owns rows [w*64, w*64+64) of the 256-row tile x all 64 cols.
// LDS swizzle: chunk slot c of row r holds global 16B-chunk (c ^ (r&7)).
__global__ __launch_bounds__(256) void bsr_gemm_kernel(
    const unsigned short* __restrict__ xb,   // bf16 [BATCH][IN_F]
    const unsigned short* __restrict__ wb,   // bf16 [NNZB][64][64] ([n][k])
    const float* __restrict__ bias,
    const int* __restrict__ crow,
    const int* __restrict__ cols,
    float* __restrict__ out) {
  __shared__ alignas(16) char smem[LDS_A_BYTES + LDS_B_BYTES];

  const int tid = threadIdx.x;
  const int w   = tid >> 6;        // wave 0..3
  const int l   = tid & 63;        // lane
  const int r   = blockIdx.x;      // block-row of W
  const int m0  = blockIdx.y * BM; // batch tile origin

  const int start = crow[r];
  const int end   = crow[r + 1];

  const int lr = l & 15;           // MFMA n/m index within 16
  const int q  = l >> 4;           // quad 0..3

  // Preload the block-row's column indices (uniform per iter via shfl).
  int cv = 0;
  if (start + l < end) cv = cols[start + l];

  f32x4 acc[4][4];
#pragma unroll
  for (int mi = 0; mi < 4; ++mi)
#pragma unroll
    for (int ni = 0; ni < 4; ++ni) {
      f32x4 z = {0.f, 0.f, 0.f, 0.f};
      acc[mi][ni] = z;
    }

  // Staging lane roles: row-within-issue = l>>3, chunk slot = l&7.
  // Swizzled global chunk = (l&7) ^ (l>>3)   (row&7 == l>>3 for all issues).
  const int swz = ((l & 7) ^ (l >> 3)) << 3;                  // element offset
  const int arow = (w << 3) + (l >> 3);                       // 0..31
  const unsigned short* agbase =
      xb + (size_t)(m0 + arow) * IN_F + swz;                  // + c*64 per block
  char* const alds = smem + (w << 10) + (l << 4);             // + it*4096
  char* const blds = smem + LDS_A_BYTES + (w << 10) + (l << 4); // + it*4096
  const int bgoff = (((w << 3) + (l >> 3)) << 6) + swz;       // elements

  for (int i = start; i < end; ++i) {
    const int c = __shfl(cv, i - start);                      // uniform
    const unsigned short* ag = agbase + (size_t)c * BS;
    const unsigned short* bg = wb + ((size_t)i << 12) + bgoff;

    __syncthreads();   // previous compute done before LDS overwrite
#pragma unroll
    for (int it = 0; it < 8; ++it)
      async_copy16(ag + (size_t)(it * 32) * IN_F, alds + it * 4096);
#pragma unroll
    for (int it = 0; it < 2; ++it)
      async_copy16(bg + it * 2048, blds + it * 4096);
    __syncthreads();   // drains vmcnt -> staged data visible

#pragma unroll
    for (int ks = 0; ks < 2; ++ks) {
      s16x8 af[4], bf[4];
#pragma unroll
      for (int mi = 0; mi < 4; ++mi)   // A[m][k], swizzled chunk lookup
        af[mi] = *(const s16x8*)(smem + ((w << 6) + (mi << 4) + lr) * 128 +
                                 ((((ks << 2) + q) ^ (l & 7)) << 4));
#pragma unroll
      for (int ni = 0; ni < 4; ++ni)   // B^T[n][k], swizzled chunk lookup
        bf[ni] = *(const s16x8*)(smem + LDS_A_BYTES + ((ni << 4) + lr) * 128 +
                                 ((((ks << 2) + q) ^ (l & 7)) << 4));
#pragma unroll
      for (int mi = 0; mi < 4; ++mi)
#pragma unroll
        for (int ni = 0; ni < 4; ++ni)
          acc[mi][ni] = __builtin_amdgcn_mfma_f32_16x16x32_bf16(
              af[mi], bf[ni], acc[mi][ni], 0, 0, 0);
    }
  }

  // Epilogue: C/D layout col=lr, row=q*4+reg. Add bias, store fp32.
  const int colg = (r << 6) + lr;
#pragma unroll
  for (int ni = 0; ni < 4; ++ni) {
    const float bv = bias[colg + (ni << 4)];
#pragma unroll
    for (int mi = 0; mi < 4; ++mi) {
      float* op = out +
          (size_t)(m0 + (w << 6) + (mi << 4) + (q << 2)) * OUT_F +
          colg + (ni << 4);
#pragma unroll
      for (int e = 0; e < 4; ++e)
        op[(size_t)e * OUT_F] = acc[mi][ni][e] + bv;
    }
  }
}

// Safety net if ws_size < 84 MB: naive fp32, one thread per output element.
__global__ void fallback_kernel(const float* __restrict__ x,
                                const float* __restrict__ vals,
                                const float* __restrict__ bias,
                                const int* __restrict__ crow,
                                const int* __restrict__ cols,
                                float* __restrict__ out) {
  int idx = blockIdx.x * 256 + threadIdx.x;
  int m = idx >> 12;
  int n = idx & 4095;
  int r = n >> 6, nl = n & 63;
  float s = 0.f;
  int e = crow[r + 1];
  for (int i = crow[r]; i < e; ++i) {
    const float* xp = x + (size_t)m * IN_F + cols[i] * 64;
    const float* wp = vals + ((size_t)i << 12) + nl * 64;
    for (int k = 0; k < 64; ++k) s += xp[k] * wp[k];
  }
  out[idx] = s + bias[n];
}

extern "C" void kernel_launch(void* const* d_in, const int* in_sizes, int n_in,
                              void* d_out, int out_size, void* d_ws,
                              size_t ws_size, hipStream_t stream) {
  const float* x    = (const float*)d_in[0];
  const float* vals = (const float*)d_in[1];
  const float* bias = (const float*)d_in[2];
  const int*   crow = (const int*)d_in[3];
  const int*   cols = (const int*)d_in[4];
  float* out = (float*)d_out;

  const size_t x_elems = (size_t)BATCH * IN_F;       // 33.5M
  const size_t w_elems = (size_t)NNZB * BS * BS;     // 8.4M
  const size_t need = (x_elems + w_elems) * 2;       // bf16 bytes, ~84 MB

  if (ws_size >= need) {
    unsigned short* xb = (unsigned short*)d_ws;
    unsigned short* wb = xb + x_elems;
    cvt_kernel<<<(int)(x_elems / 4 / 256), 256, 0, stream>>>(
        (const float4*)x, (ushort4*)xb, (int)(x_elems / 4));
    cvt_kernel<<<(int)(w_elems / 4 / 256), 256, 0, stream>>>(
        (const float4*)vals, (ushort4*)wb, (int)(w_elems / 4));
    dim3 grid(NROW, BATCH / BM);   // r fast => 64 block-rows share an x slab in L2
    bsr_gemm_kernel<<<grid, 256, 0, stream>>>(xb, wb, bias, crow, cols, out);
  } else {
    fallback_kernel<<<(BATCH * OUT_F) / 256, 256, 0, stream>>>(
        x, vals, bias, crow, cols, out);
  }
}

// Round 3
// 373.804 us; speedup vs baseline: 1.0988x; 1.0988x over previous
//
#include <hip/hip_runtime.h>
#include <stdint.h>

// Block-sparse linear: out[8192,4096] = x @ W^T + bias, W BSR 64x64 blocks.
// R3: pair two same-parity block-rows (identical col sets in this structure)
// per workgroup -> N=128 tile sharing one A-tile. Staged bytes/FLOP drops
// 0.0195 -> 0.0114 (the measured limiter: R2 showed 704 TF == m97-model
// prediction for 40KB-per-2.1MFLOP staging; conflicts already 0).
// Generic BSR correctness: runtime merge of the two sorted col lists with
// predicated staging/MFMA; optimal when the sets coincide.

#define BATCH   8192
#define IN_F    4096
#define OUT_F   4096
#define BS      64
#define NROW    64
#define NNZB    2048
#define BM      256                        // batch rows per workgroup
#define LDS_A_BYTES (BM * BS * 2)          // 32768
#define LDS_B_BYTES (2 * BS * BS * 2)      // 16384 (two W blocks)

typedef float f32x4 __attribute__((ext_vector_type(4)));
typedef short s16x8 __attribute__((ext_vector_type(8)));   // 8 x bf16

__device__ __forceinline__ void async_copy16(const void* g, void* l) {
  // global -> LDS direct DMA, 16 B/lane. LDS dest = wave base + lane*16.
  __builtin_amdgcn_global_load_lds(
      (__attribute__((address_space(1))) void*)g,
      (__attribute__((address_space(3))) void*)l, 16, 0, 0);
}

__device__ __forceinline__ unsigned short f32_to_bf16(float f) {
  union { float f; uint32_t u; } v; v.f = f;
  return (unsigned short)((v.u + 0x7FFFu + ((v.u >> 16) & 1u)) >> 16);
}

__global__ void cvt_kernel(const float4* __restrict__ in,
                           ushort4* __restrict__ out, int n4) {
  int i = blockIdx.x * blockDim.x + threadIdx.x;
  if (i < n4) {
    float4 v = in[i];
    ushort4 o;
    o.x = f32_to_bf16(v.x); o.y = f32_to_bf16(v.y);
    o.z = f32_to_bf16(v.z); o.w = f32_to_bf16(v.w);
    out[i] = o;
  }
}

// GEMM: grid (NROW/2=32 pairs, BATCH/BM=32), block 512 = 8 waves.
// Pair p -> rows rA = (p>>1)*4 + (p&1), rB = rA+2 (same parity -> same cols
// in this dataset; merge loop handles arbitrary overlap).
// Wave w: wm=w&3 (64-row m-quarter), wn=w>>2 (which block-row).
// LDS swizzle (verified 0 conflicts in R2): chunk slot s of row r holds
// global 16B-chunk (s ^ (r&7)).
__global__ __launch_bounds__(512) void bsr_gemm_pair_kernel(
    const unsigned short* __restrict__ xb,   // bf16 [BATCH][IN_F]
    const unsigned short* __restrict__ wb,   // bf16 [NNZB][64][64] ([n][k])
    const float* __restrict__ bias,
    const int* __restrict__ crow,
    const int* __restrict__ cols,
    float* __restrict__ out) {
  __shared__ alignas(16) char smem[LDS_A_BYTES + LDS_B_BYTES];

  const int tid = threadIdx.x;
  const int w   = tid >> 6;        // wave 0..7
  const int l   = tid & 63;        // lane
  const int wm  = w & 3;           // m-quarter
  const int wn  = w >> 2;          // block-row within pair
  const int p   = blockIdx.x;
  const int rA  = ((p >> 1) << 2) + (p & 1);
  const int rB  = rA + 2;
  const int m0  = blockIdx.y * BM;

  const int startA = crow[rA], endA = crow[rA + 1];
  const int startB = crow[rB], endB = crow[rB + 1];

  const int lr = l & 15;           // MFMA m/n index within 16
  const int q  = l >> 4;           // quad 0..3

  // Preload both col lists into lane registers (uniform per iter via shfl).
  int cvA = (startA + l < endA) ? cols[startA + l] : 0;
  int cvB = (startB + l < endB) ? cols[startB + l] : 0;

  f32x4 acc[4][4];
#pragma unroll
  for (int mi = 0; mi < 4; ++mi)
#pragma unroll
    for (int ni = 0; ni < 4; ++ni) {
      f32x4 z = {0.f, 0.f, 0.f, 0.f};
      acc[mi][ni] = z;
    }

  // Staging lane roles (512 threads): row-within-issue = tid>>3 (0..63),
  // chunk slot = tid&7, swizzled global chunk = slot ^ (row&7).
  const int srow = tid >> 3;
  const int sswz = ((tid & 7) ^ (srow & 7)) << 3;              // elements
  const unsigned short* agbase =
      xb + (size_t)(m0 + srow) * IN_F + sswz;                  // + c*64, +it*64*IN_F
  char* const alds = smem + tid * 16;                          // + it*8192
  char* const blds = smem + LDS_A_BYTES + tid * 16;            // + region*8192
  const int bgoff = (srow << 6) + sswz;                        // elements

  int ia = startA, ib = startB;
  while ((ia < endA) || (ib < endB)) {
    const int ca = (ia < endA) ? __shfl(cvA, ia - startA) : 0x7fffffff;
    const int cb = (ib < endB) ? __shfl(cvB, ib - startB) : 0x7fffffff;
    const int c = min(ca, cb);
    const bool hasA = (ca == c);
    const bool hasB = (cb == c);
    const int iA = ia, iB = ib;
    if (hasA) ++ia;
    if (hasB) ++ib;

    __syncthreads();   // previous compute done before LDS overwrite
    const unsigned short* ag = agbase + (size_t)c * BS;
#pragma unroll
    for (int it = 0; it < 4; ++it)                 // A: 256 rows x 128 B
      async_copy16(ag + (size_t)(it * 64) * IN_F, alds + it * 8192);
    if (hasA)                                       // B block for rA
      async_copy16(wb + ((size_t)iA << 12) + bgoff, blds);
    if (hasB)                                       // B block for rB
      async_copy16(wb + ((size_t)iB << 12) + bgoff, blds + 8192);
    __syncthreads();   // drains vmcnt -> staged data visible

    const bool active = wn ? hasB : hasA;
    if (active) {
#pragma unroll
      for (int ks = 0; ks < 2; ++ks) {
        const int chunk = (((ks << 2) + q) ^ (l & 7)) << 4;    // bytes
        s16x8 af[4], bf[4];
#pragma unroll
        for (int mi = 0; mi < 4; ++mi)   // A[m][k], swizzled chunk
          af[mi] = *(const s16x8*)(smem +
                     ((wm << 6) + (mi << 4) + lr) * 128 + chunk);
#pragma unroll
        for (int ni = 0; ni < 4; ++ni)   // B^T[n][k], region wn
          bf[ni] = *(const s16x8*)(smem + LDS_A_BYTES + (wn << 13) +
                     ((ni << 4) + lr) * 128 + chunk);
#pragma unroll
        for (int mi = 0; mi < 4; ++mi)
#pragma unroll
          for (int ni = 0; ni < 4; ++ni)
            acc[mi][ni] = __builtin_amdgcn_mfma_f32_16x16x32_bf16(
                af[mi], bf[ni], acc[mi][ni], 0, 0, 0);
      }
    }
  }

  // Epilogue: C/D layout col=lr, row=q*4+reg. Add bias, store fp32.
  const int rW = wn ? rB : rA;
  const int colg = (rW << 6) + lr;
#pragma unroll
  for (int ni = 0; ni < 4; ++ni) {
    const float bv = bias[colg + (ni << 4)];
#pragma unroll
    for (int mi = 0; mi < 4; ++mi) {
      float* op = out +
          (size_t)(m0 + (wm << 6) + (mi << 4) + (q << 2)) * OUT_F +
          colg + (ni << 4);
#pragma unroll
      for (int e = 0; e < 4; ++e)
        op[(size_t)e * OUT_F] = acc[mi][ni][e] + bv;
    }
  }
}

// Safety net if ws_size < 84 MB: naive fp32, one thread per output element.
__global__ void fallback_kernel(const float* __restrict__ x,
                                const float* __restrict__ vals,
                                const float* __restrict__ bias,
                                const int* __restrict__ crow,
                                const int* __restrict__ cols,
                                float* __restrict__ out) {
  int idx = blockIdx.x * 256 + threadIdx.x;
  int m = idx >> 12;
  int n = idx & 4095;
  int r = n >> 6, nl = n & 63;
  float s = 0.f;
  int e = crow[r + 1];
  for (int i = crow[r]; i < e; ++i) {
    const float* xp = x + (size_t)m * IN_F + cols[i] * 64;
    const float* wp = vals + ((size_t)i << 12) + nl * 64;
    for (int k = 0; k < 64; ++k) s += xp[k] * wp[k];
  }
  out[idx] = s + bias[n];
}

extern "C" void kernel_launch(void* const* d_in, const int* in_sizes, int n_in,
                              void* d_out, int out_size, void* d_ws,
                              size_t ws_size, hipStream_t stream) {
  const float* x    = (const float*)d_in[0];
  const float* vals = (const float*)d_in[1];
  const float* bias = (const float*)d_in[2];
  const int*   crow = (const int*)d_in[3];
  const int*   cols = (const int*)d_in[4];
  float* out = (float*)d_out;

  const size_t x_elems = (size_t)BATCH * IN_F;       // 33.5M
  const size_t w_elems = (size_t)NNZB * BS * BS;     // 8.4M
  const size_t need = (x_elems + w_elems) * 2;       // bf16 bytes, ~84 MB

  if (ws_size >= need) {
    unsigned short* xb = (unsigned short*)d_ws;
    unsigned short* wb = xb + x_elems;
    cvt_kernel<<<(int)(x_elems / 4 / 256), 256, 0, stream>>>(
        (const float4*)x, (ushort4*)xb, (int)(x_elems / 4));
    cvt_kernel<<<(int)(w_elems / 4 / 256), 256, 0, stream>>>(
        (const float4*)vals, (ushort4*)wb, (int)(w_elems / 4));
    dim3 grid(NROW / 2, BATCH / BM);  // pair-fast: same x-slab hot in L2
    bsr_gemm_pair_kernel<<<grid, 512, 0, stream>>>(xb, wb, bias, crow, cols,
                                                   out);
  } else {
    fallback_kernel<<<(BATCH * OUT_F) / 256, 256, 0, stream>>>(
        x, vals, bias, crow, cols, out);
  }
}